// Round 1
// baseline (1030.430 us; speedup 1.0000x reference)
//
#include <hip/hip_runtime.h>
#include <hip/hip_bf16.h>
#include <stdint.h>

// Attention_47528108097749: llama attention block. f32 in/out, bf16 MFMA inside.
// B=2, T=2048, D=4096, H=32, KV=8, HD=128. start_pos=0, mask unused (full attn).

typedef short bf16x8 __attribute__((ext_vector_type(8)));
typedef float f32x4  __attribute__((ext_vector_type(4)));

#define GLB_AS(p) ((__attribute__((address_space(1))) void*)(p))
#define LDS_AS(p) ((__attribute__((address_space(3))) void*)(p))

__device__ __forceinline__ float bf2f(ushort u) {
    union { unsigned int i; float f; } v; v.i = ((unsigned int)u) << 16; return v.f;
}
__device__ __forceinline__ ushort f2bf(float f) {
    union { float f; unsigned int i; } v; v.f = f;
    unsigned int r = v.i + 0x7FFFu + ((v.i >> 16) & 1u);   // RNE
    return (ushort)(r >> 16);
}
__device__ __forceinline__ unsigned int pk_bf16(float a, float b) {
    return (unsigned int)f2bf(a) | ((unsigned int)f2bf(b) << 16);
}
// HW packed f32->bf16 (RNE via MODE default); lo = src0 (T12, learn_hip m214v22)
__device__ __forceinline__ unsigned int cvtpk2(float lo, float hi) {
    unsigned int r;
    asm("v_cvt_pk_bf16_f32 %0, %1, %2" : "=v"(r) : "v"(lo), "v"(hi));
    return r;
}
__device__ __forceinline__ void store_c(ushort* p, float v) { *p = f2bf(v); }
__device__ __forceinline__ void store_c(float*  p, float v) { *p = v; }

// ---------------------------------------------------------------------------
__global__ __launch_bounds__(256) void cast_f2b(
    const float4* __restrict__ src, ushort4* __restrict__ dst, int n4)
{
    int i = blockIdx.x * 256 + threadIdx.x;
    if (i < n4) {
        float4 v = src[i];
        ushort4 o;
        o.x = f2bf(v.x); o.y = f2bf(v.y); o.z = f2bf(v.z); o.w = f2bf(v.w);
        dst[i] = o;
    }
}

// ---------------------------------------------------------------------------
// NT GEMM (m97 structure): C[m][n] = sum_k A[m][k]*B[n][k], bf16 in, OT out.
// ---------------------------------------------------------------------------
template <typename OT>
__global__ __launch_bounds__(256) void gemm_nt(
    const ushort* __restrict__ A, const ushort* __restrict__ B,
    OT* __restrict__ C, int M, int N, int K)
{
    __shared__ __align__(16) ushort lA[128 * 32];
    __shared__ __align__(16) ushort lB[128 * 32];

    const int tid  = threadIdx.x;
    const int lane = tid & 63;
    const int w    = tid >> 6;
    const int wm   = w >> 1, wn = w & 1;
    const int quad = lane >> 4, l16 = lane & 15;
    const int bm   = blockIdx.y * 128, bn = blockIdx.x * 128;

    f32x4 acc[4][4];
#pragma unroll
    for (int i = 0; i < 4; i++)
#pragma unroll
        for (int j = 0; j < 4; j++) acc[i][j] = (f32x4){0.f, 0.f, 0.f, 0.f};

    const ushort* pa0 = A + (size_t)(bm + (tid >> 2)) * K + (tid & 3) * 8;
    const ushort* pb0 = B + (size_t)(bn + (tid >> 2)) * K + (tid & 3) * 8;
    char* ldsA0 = (char*)lA + (tid & 192) * 16;
    char* ldsA1 = ldsA0 + 4096;
    char* ldsB0 = (char*)lB + (tid & 192) * 16;
    char* ldsB1 = ldsB0 + 4096;
    const size_t rowskip = (size_t)64 * K;

    for (int k0 = 0; k0 < K; k0 += 32) {
        __builtin_amdgcn_global_load_lds(GLB_AS(pa0 + k0),           LDS_AS(ldsA0), 16, 0, 0);
        __builtin_amdgcn_global_load_lds(GLB_AS(pa0 + rowskip + k0), LDS_AS(ldsA1), 16, 0, 0);
        __builtin_amdgcn_global_load_lds(GLB_AS(pb0 + k0),           LDS_AS(ldsB0), 16, 0, 0);
        __builtin_amdgcn_global_load_lds(GLB_AS(pb0 + rowskip + k0), LDS_AS(ldsB1), 16, 0, 0);
        __syncthreads();

        bf16x8 a[4], b[4];
#pragma unroll
        for (int i = 0; i < 4; i++)
            a[i] = *(const bf16x8*)&lA[(wm * 64 + i * 16 + l16) * 32 + quad * 8];
#pragma unroll
        for (int j = 0; j < 4; j++)
            b[j] = *(const bf16x8*)&lB[(wn * 64 + j * 16 + l16) * 32 + quad * 8];
#pragma unroll
        for (int i = 0; i < 4; i++)
#pragma unroll
            for (int j = 0; j < 4; j++)
                acc[i][j] = __builtin_amdgcn_mfma_f32_16x16x32_bf16(a[i], b[j], acc[i][j], 0, 0, 0);
        __syncthreads();
    }

#pragma unroll
    for (int i = 0; i < 4; i++)
#pragma unroll
        for (int j = 0; j < 4; j++)
#pragma unroll
            for (int r = 0; r < 4; r++) {
                int row = bm + wm * 64 + i * 16 + quad * 4 + r;
                int col = bn + wn * 64 + j * 16 + l16;
                store_c(&C[(size_t)row * N + col], acc[i][j][r]);
            }
}

// ---------------------------------------------------------------------------
// RoPE in-place on bf16 X; row stride ldx, cos/sin f32 [2048][64].
// Scale folds attention 1/sqrt(HD) (and log2(e) for exp2-domain softmax) into Q.
// ---------------------------------------------------------------------------
__global__ __launch_bounds__(256) void rope_kernel(
    ushort* __restrict__ X, const float* __restrict__ cosv,
    const float* __restrict__ sinv, int ldx, int tprs, float scale)
{
    int gid = blockIdx.x * 256 + threadIdx.x;
    int m  = gid >> tprs;
    int pi = (gid & ((1 << tprs) - 1)) * 4;
    int t  = m & 2047;
    int i  = pi & 63;
    float4 c4 = *(const float4*)&cosv[t * 64 + i];
    float4 s4 = *(const float4*)&sinv[t * 64 + i];
    ushort* px = X + (size_t)m * ldx + pi * 2;
    uint4 d = *(const uint4*)px;
    unsigned int parts[4] = {d.x, d.y, d.z, d.w};
    float cc[4] = {c4.x, c4.y, c4.z, c4.w};
    float ss[4] = {s4.x, s4.y, s4.z, s4.w};
#pragma unroll
    for (int p = 0; p < 4; p++) {
        float re = bf2f((ushort)(parts[p] & 0xffffu));
        float im = bf2f((ushort)(parts[p] >> 16));
        float re2 = (re * cc[p] - im * ss[p]) * scale;
        float im2 = (re * ss[p] + im * cc[p]) * scale;
        parts[p] = pk_bf16(re2, im2);
    }
    *(uint4*)px = make_uint4(parts[0], parts[1], parts[2], parts[3]);
}

// ---------------------------------------------------------------------------
// V transpose out of fused KV: KV rows (b,t) stride 2048, V = cols 1024..2047.
// Vt[b][n][t], n=(kv,d) in 0..1023.
// ---------------------------------------------------------------------------
__global__ __launch_bounds__(256) void transpose_v(
    const ushort* __restrict__ KV, ushort* __restrict__ Vt)
{
    __shared__ ushort tile[32][33];
    int n0 = blockIdx.x * 32, m0 = blockIdx.y * 32;
    int tx = threadIdx.x & 31, ty = threadIdx.x >> 5;
#pragma unroll
    for (int r = ty; r < 32; r += 8)
        tile[r][tx] = KV[(size_t)(m0 + r) * 2048 + 1024 + n0 + tx];
    __syncthreads();
    int b  = m0 >> 11;
    int t0 = m0 & 2047;
#pragma unroll
    for (int r = ty; r < 32; r += 8)
        Vt[(size_t)b * 2097152 + (size_t)(n0 + r) * 2048 + t0 + tx] = tile[tx][r];
}

// ---------------------------------------------------------------------------
// Flash attention, S^T scheme, XOR-swizzled LDS tiles (conflict-free b128).
// Grid (32 qtiles, 32 h, 2 b), 4 waves x 16 q. Key tile = 64.
// lK stored as [key][chunk ^ (key&15)] (16-B chunks); lV as [d][chunk ^ (d&7)].
// Swizzle applied by permuting global_load_lds SOURCE addresses (dest must
// stay lane-contiguous), un-applied in the ds_read addressing.
//
// R1 changes (T3-min-2phase + T13 + T12-pack):
//  - double-buffered K/V LDS; next tile is STAGEd BEFORE computing the current
//    one, so the vmcnt(0) drain inside the single per-tile __syncthreads is
//    covered by QK^T+softmax+PV (previously: stage->sync = zero overlap,
//    2 barriers/tile).
//  - defer-max: rescale o only when __any(tmax > m + 8) (log2 domain);
//    p bounded by 2^8 which bf16 handles at unchanged relative precision.
//  - softmax in exp2 domain (log2(e) folded into Q scale on host).
//  - v_cvt_pk_bf16_f32 for P-pack + epilogue (1 op per 2 values vs ~8).
// ---------------------------------------------------------------------------
__global__ __launch_bounds__(256) void flash_attn(
    const ushort* __restrict__ Q, const ushort* __restrict__ KV,
    const ushort* __restrict__ Vt, ushort* __restrict__ ctx)
{
    __shared__ __align__(16) ushort lK[2][64 * 128];    // [buf][key][d-swz] 32 KB
    __shared__ __align__(16) ushort lV[2][128 * 64];    // [buf][d][s-swz]   32 KB
    __shared__ __align__(16) ushort lP[4 * 16 * 72];    // per-wave [q][72]   9 KB

    const int qt = blockIdx.x, h = blockIdx.y, b = blockIdx.z;
    const int kv = h >> 2;
    const int tid = threadIdx.x, lane = tid & 63, w = tid >> 6;
    const int quad = lane >> 4, l16 = lane & 15;

    const int q0 = qt * 64 + w * 16;
    const size_t qrow = (size_t)(b * 2048 + q0 + l16) * 4096 + h * 128;
    bf16x8 bQ[4];
#pragma unroll
    for (int ks = 0; ks < 4; ks++)
        bQ[ks] = *(const bf16x8*)&Q[qrow + ks * 32 + quad * 8];

    f32x4 o[8];
#pragma unroll
    for (int dc = 0; dc < 8; dc++) o[dc] = (f32x4){0.f, 0.f, 0.f, 0.f};
    float m = -1e30f, l = 0.f;

    const ushort* gK = KV + (size_t)(b * 2048) * 2048 + kv * 128;   // stride 2048
    const ushort* gV = Vt + (size_t)(b * 8 + kv) * 2048 * 128;      // [d][t]
    ushort* pw = &lP[w * 16 * 72];

    // staging decomposition (swizzled source chunks):
    //  K: slot = rep*256+tid = key*16+dslot; key = rep*16+(tid>>4), dslot = tid&15
    //     global d-chunk = dslot ^ (key & 15) = dsub ^ keyb
    //  V: slot = d*8+sslot; d = rep*32+(tid>>3), sslot = tid&7
    //     global s-chunk = sslot ^ (d & 7) = ssub ^ (db & 7)
    const int keyb = tid >> 4, dsub = tid & 15;
    const int db   = tid >> 3, ssub = tid & 7;
    const ushort* baseK = gK + (size_t)keyb * 2048 + (dsub ^ keyb) * 8;
    const ushort* baseV = gV + (size_t)db * 2048 + (ssub ^ (db & 7)) * 8;
    char* ldsK = (char*)lK + (tid & 192) * 16;   // wave-uniform sub-base
    char* ldsV = (char*)lV + (tid & 192) * 16;

    auto STAGE = [&](int s0, int bsel) {
        char* dK = ldsK + bsel * 16384;
        char* dV = ldsV + bsel * 16384;
#pragma unroll
        for (int rep = 0; rep < 4; rep++) {
            __builtin_amdgcn_global_load_lds(
                GLB_AS(baseK + (size_t)(s0 + rep * 16) * 2048),
                LDS_AS(dK + rep * 4096), 16, 0, 0);
            __builtin_amdgcn_global_load_lds(
                GLB_AS(baseV + rep * 65536 + s0),
                LDS_AS(dV + rep * 4096), 16, 0, 0);
        }
    };

    STAGE(0, 0);
    __syncthreads();

    int buf = 0;
    for (int it = 0; it < 32; ++it) {
        if (it < 31) STAGE((it + 1) * 64, buf ^ 1);   // in flight across compute

        const ushort* Kb = lK[buf];
        const ushort* Vb = lV[buf];

        // S^T[key][q]: A = K rows (16 keys/group), B = Q
        f32x4 scT[4];
#pragma unroll
        for (int g = 0; g < 4; g++) scT[g] = (f32x4){0.f, 0.f, 0.f, 0.f};
#pragma unroll
        for (int g = 0; g < 4; g++)
#pragma unroll
            for (int ks = 0; ks < 4; ks++) {
                // key = g*16+l16; chunk ks*4+quad, swizzled by key&15 = l16
                bf16x8 aK = *(const bf16x8*)&Kb[(g * 16 + l16) * 128 + ((ks * 4 + quad) ^ l16) * 8];
                scT[g] = __builtin_amdgcn_mfma_f32_16x16x32_bf16(aK, bQ[ks], scT[g], 0, 0, 0);
            }

        // online softmax (exp2 domain): lane holds 16 keys for q = l16
        float tmax = scT[0][0];
#pragma unroll
        for (int g = 0; g < 4; g++)
#pragma unroll
            for (int r = 0; r < 4; r++) tmax = fmaxf(tmax, scT[g][r]);
        tmax = fmaxf(tmax, __shfl_xor(tmax, 16, 64));
        tmax = fmaxf(tmax, __shfl_xor(tmax, 32, 64));

        if (__any(tmax > m + 8.f)) {     // defer-max: skip rescale while bounded
            float mnew = fmaxf(m, tmax);
            float alpha = exp2f(m - mnew);
            m = mnew;
            l *= alpha;
#pragma unroll
            for (int dc = 0; dc < 8; dc++)
#pragma unroll
                for (int r = 0; r < 4; r++) o[dc][r] *= alpha;
        }

        float p[16];
        float ts = 0.f;
#pragma unroll
        for (int i = 0; i < 16; i++) {
            p[i] = exp2f(scT[i >> 2][i & 3] - m);
            ts += p[i];
        }
        ts += __shfl_xor(ts, 16, 64);
        ts += __shfl_xor(ts, 32, 64);
        l += ts;

        // P^T -> LDS [q][s] (s = g*16 + quad*4 + r), b64 writes, stride 72
#pragma unroll
        for (int g = 0; g < 4; g++) {
            uint2 pk;
            pk.x = cvtpk2(p[g * 4 + 0], p[g * 4 + 1]);
            pk.y = cvtpk2(p[g * 4 + 2], p[g * 4 + 3]);
            *(uint2*)&pw[l16 * 72 + g * 16 + quad * 4] = pk;
        }
        bf16x8 bP[2];
#pragma unroll
        for (int c = 0; c < 2; c++)
            bP[c] = *(const bf16x8*)&pw[l16 * 72 + c * 32 + quad * 8];

        // O^T += V^T * P^T
#pragma unroll
        for (int dc = 0; dc < 8; dc++)
#pragma unroll
            for (int c = 0; c < 2; c++) {
                // d = dc*16+l16; chunk c*4+quad, swizzled by d&7 = l16&7
                bf16x8 aV = *(const bf16x8*)&Vb[(dc * 16 + l16) * 64 + ((c * 4 + quad) ^ (l16 & 7)) * 8];
                o[dc] = __builtin_amdgcn_mfma_f32_16x16x32_bf16(aV, bP[c], o[dc], 0, 0, 0);
            }
        __syncthreads();   // drains this tile's prefetch (vmcnt 0) + releases buf
        buf ^= 1;
    }

    // epilogue: lane has O^T[d = dc*16+quad*4+r][q = l16]
    float inv = 1.0f / l;
#pragma unroll
    for (int dc = 0; dc < 8; dc++) {
        uint2 pk;
        pk.x = cvtpk2(o[dc][0] * inv, o[dc][1] * inv);
        pk.y = cvtpk2(o[dc][2] * inv, o[dc][3] * inv);
        *(uint2*)&ctx[qrow + dc * 16 + quad * 4] = pk;
    }
}

// ---------------------------------------------------------------------------
extern "C" void kernel_launch(void* const* d_in, const int* in_sizes, int n_in,
                              void* d_out, int out_size, void* d_ws, size_t ws_size,
                              hipStream_t stream)
{
    const float* x    = (const float*)d_in[0];
    const float* wq   = (const float*)d_in[1];
    const float* wk   = (const float*)d_in[2];
    const float* wv   = (const float*)d_in[3];
    const float* wo   = (const float*)d_in[4];
    const float* cosv = (const float*)d_in[7];
    const float* sinv = (const float*)d_in[8];
    float* out = (float*)d_out;

    // workspace (ushort units), 128 MB total via aliasing
    ushort* Xb   = (ushort*)d_ws;                    // 16M: x bf16; later ctx
    ushort* ctx  = Xb;
    ushort* Wbig = Xb   + (size_t)16 * 1024 * 1024;  // 16M: wq, then wo
    ushort* Wsm  = Wbig + (size_t)16 * 1024 * 1024;  //  8M: [wk;wv]; later Vt
    ushort* Vt   = Wsm;
    ushort* Q    = Wsm  + (size_t)8  * 1024 * 1024;  // 16M
    ushort* KV   = Q    + (size_t)16 * 1024 * 1024;  //  8M: [K|V] cols, stride 2048

    dim3 blk(256);
    cast_f2b<<<16384, blk, 0, stream>>>((const float4*)x,  (ushort4*)Xb,   4194304);
    cast_f2b<<<16384, blk, 0, stream>>>((const float4*)wq, (ushort4*)Wbig, 4194304);
    cast_f2b<<<4096,  blk, 0, stream>>>((const float4*)wk, (ushort4*)Wsm,  1048576);
    cast_f2b<<<4096,  blk, 0, stream>>>((const float4*)wv, (ushort4*)(Wsm + (size_t)4194304), 1048576);

    gemm_nt<<<dim3(32, 32), blk, 0, stream>>>(Xb, Wbig, Q,  4096, 4096, 4096);
    gemm_nt<<<dim3(16, 32), blk, 0, stream>>>(Xb, Wsm,  KV, 4096, 2048, 4096);

    cast_f2b<<<16384, blk, 0, stream>>>((const float4*)wo, (ushort4*)Wbig, 4194304);

    // Q scale = 1/sqrt(128) * log2(e)  (softmax runs in exp2 domain)
    rope_kernel<<<8192, blk, 0, stream>>>(Q,  cosv, sinv, 4096, 9,
                                          0.08838834764831845f * 1.4426950408889634f);
    rope_kernel<<<2048, blk, 0, stream>>>(KV, cosv, sinv, 2048, 7, 1.0f);
    transpose_v<<<dim3(32, 128), blk, 0, stream>>>(KV, Vt);

    flash_attn<<<dim3(32, 32, 2), blk, 0, stream>>>(Q, KV, Vt, ctx);

    gemm_nt<<<dim3(32, 32), blk, 0, stream>>>(ctx, Wbig, out, 4096, 4096, 4096);
}

// Round 2
// 963.385 us; speedup vs baseline: 1.0696x; 1.0696x over previous
//
#include <hip/hip_runtime.h>
#include <hip/hip_bf16.h>
#include <stdint.h>

// Attention_47528108097749: llama attention block. f32 in/out, bf16 MFMA inside.
// B=2, T=2048, D=4096, H=32, KV=8, HD=128. start_pos=0, mask unused (full attn).

typedef short bf16x8 __attribute__((ext_vector_type(8)));
typedef float f32x4  __attribute__((ext_vector_type(4)));

#define GLB_AS(p) ((__attribute__((address_space(1))) void*)(p))
#define LDS_AS(p) ((__attribute__((address_space(3))) void*)(p))

__device__ __forceinline__ float bf2f(ushort u) {
    union { unsigned int i; float f; } v; v.i = ((unsigned int)u) << 16; return v.f;
}
__device__ __forceinline__ ushort f2bf(float f) {
    union { float f; unsigned int i; } v; v.f = f;
    unsigned int r = v.i + 0x7FFFu + ((v.i >> 16) & 1u);   // RNE
    return (ushort)(r >> 16);
}
__device__ __forceinline__ unsigned int pk_bf16(float a, float b) {
    return (unsigned int)f2bf(a) | ((unsigned int)f2bf(b) << 16);
}
// HW packed f32->bf16 (RNE); lo = src0
__device__ __forceinline__ unsigned int cvtpk2(float lo, float hi) {
    unsigned int r;
    asm("v_cvt_pk_bf16_f32 %0, %1, %2" : "=v"(r) : "v"(lo), "v"(hi));
    return r;
}
__device__ __forceinline__ void store_c(ushort* p, float v) { *p = f2bf(v); }
__device__ __forceinline__ void store_c(float*  p, float v) { *p = v; }

// ---------------------------------------------------------------------------
__global__ __launch_bounds__(256) void cast_f2b(
    const float4* __restrict__ src, ushort4* __restrict__ dst, int n4)
{
    int i = blockIdx.x * 256 + threadIdx.x;
    if (i < n4) {
        float4 v = src[i];
        ushort4 o;
        o.x = f2bf(v.x); o.y = f2bf(v.y); o.z = f2bf(v.z); o.w = f2bf(v.w);
        dst[i] = o;
    }
}

// ---------------------------------------------------------------------------
// NT GEMM (m97 structure): C[m][n] = sum_k A[m][k]*B[n][k], bf16 in, OT out.
// ---------------------------------------------------------------------------
template <typename OT>
__global__ __launch_bounds__(256) void gemm_nt(
    const ushort* __restrict__ A, const ushort* __restrict__ B,
    OT* __restrict__ C, int M, int N, int K)
{
    __shared__ __align__(16) ushort lA[128 * 32];
    __shared__ __align__(16) ushort lB[128 * 32];

    const int tid  = threadIdx.x;
    const int lane = tid & 63;
    const int w    = tid >> 6;
    const int wm   = w >> 1, wn = w & 1;
    const int quad = lane >> 4, l16 = lane & 15;
    const int bm   = blockIdx.y * 128, bn = blockIdx.x * 128;

    f32x4 acc[4][4];
#pragma unroll
    for (int i = 0; i < 4; i++)
#pragma unroll
        for (int j = 0; j < 4; j++) acc[i][j] = (f32x4){0.f, 0.f, 0.f, 0.f};

    const ushort* pa0 = A + (size_t)(bm + (tid >> 2)) * K + (tid & 3) * 8;
    const ushort* pb0 = B + (size_t)(bn + (tid >> 2)) * K + (tid & 3) * 8;
    char* ldsA0 = (char*)lA + (tid & 192) * 16;
    char* ldsA1 = ldsA0 + 4096;
    char* ldsB0 = (char*)lB + (tid & 192) * 16;
    char* ldsB1 = ldsB0 + 4096;
    const size_t rowskip = (size_t)64 * K;

    for (int k0 = 0; k0 < K; k0 += 32) {
        __builtin_amdgcn_global_load_lds(GLB_AS(pa0 + k0),           LDS_AS(ldsA0), 16, 0, 0);
        __builtin_amdgcn_global_load_lds(GLB_AS(pa0 + rowskip + k0), LDS_AS(ldsA1), 16, 0, 0);
        __builtin_amdgcn_global_load_lds(GLB_AS(pb0 + k0),           LDS_AS(ldsB0), 16, 0, 0);
        __builtin_amdgcn_global_load_lds(GLB_AS(pb0 + rowskip + k0), LDS_AS(ldsB1), 16, 0, 0);
        __syncthreads();

        bf16x8 a[4], b[4];
#pragma unroll
        for (int i = 0; i < 4; i++)
            a[i] = *(const bf16x8*)&lA[(wm * 64 + i * 16 + l16) * 32 + quad * 8];
#pragma unroll
        for (int j = 0; j < 4; j++)
            b[j] = *(const bf16x8*)&lB[(wn * 64 + j * 16 + l16) * 32 + quad * 8];
#pragma unroll
        for (int i = 0; i < 4; i++)
#pragma unroll
            for (int j = 0; j < 4; j++)
                acc[i][j] = __builtin_amdgcn_mfma_f32_16x16x32_bf16(a[i], b[j], acc[i][j], 0, 0, 0);
        __syncthreads();
    }

#pragma unroll
    for (int i = 0; i < 4; i++)
#pragma unroll
        for (int j = 0; j < 4; j++)
#pragma unroll
            for (int r = 0; r < 4; r++) {
                int row = bm + wm * 64 + i * 16 + quad * 4 + r;
                int col = bn + wn * 64 + j * 16 + l16;
                store_c(&C[(size_t)row * N + col], acc[i][j][r]);
            }
}

// ---------------------------------------------------------------------------
// RoPE in-place on bf16 X; row stride ldx, cos/sin f32 [2048][64].
// Scale folds attention 1/sqrt(HD) (and log2(e) for exp2-domain softmax) into Q.
// ---------------------------------------------------------------------------
__global__ __launch_bounds__(256) void rope_kernel(
    ushort* __restrict__ X, const float* __restrict__ cosv,
    const float* __restrict__ sinv, int ldx, int tprs, float scale)
{
    int gid = blockIdx.x * 256 + threadIdx.x;
    int m  = gid >> tprs;
    int pi = (gid & ((1 << tprs) - 1)) * 4;
    int t  = m & 2047;
    int i  = pi & 63;
    float4 c4 = *(const float4*)&cosv[t * 64 + i];
    float4 s4 = *(const float4*)&sinv[t * 64 + i];
    ushort* px = X + (size_t)m * ldx + pi * 2;
    uint4 d = *(const uint4*)px;
    unsigned int parts[4] = {d.x, d.y, d.z, d.w};
    float cc[4] = {c4.x, c4.y, c4.z, c4.w};
    float ss[4] = {s4.x, s4.y, s4.z, s4.w};
#pragma unroll
    for (int p = 0; p < 4; p++) {
        float re = bf2f((ushort)(parts[p] & 0xffffu));
        float im = bf2f((ushort)(parts[p] >> 16));
        float re2 = (re * cc[p] - im * ss[p]) * scale;
        float im2 = (re * ss[p] + im * cc[p]) * scale;
        parts[p] = pk_bf16(re2, im2);
    }
    *(uint4*)px = make_uint4(parts[0], parts[1], parts[2], parts[3]);
}

// ---------------------------------------------------------------------------
// V transpose out of fused KV: KV rows (b,t) stride 2048, V = cols 1024..2047.
// Vt[b][n][t], n=(kv,d) in 0..1023.
// ---------------------------------------------------------------------------
__global__ __launch_bounds__(256) void transpose_v(
    const ushort* __restrict__ KV, ushort* __restrict__ Vt)
{
    __shared__ ushort tile[32][33];
    int n0 = blockIdx.x * 32, m0 = blockIdx.y * 32;
    int tx = threadIdx.x & 31, ty = threadIdx.x >> 5;
#pragma unroll
    for (int r = ty; r < 32; r += 8)
        tile[r][tx] = KV[(size_t)(m0 + r) * 2048 + 1024 + n0 + tx];
    __syncthreads();
    int b  = m0 >> 11;
    int t0 = m0 & 2047;
#pragma unroll
    for (int r = ty; r < 32; r += 8)
        Vt[(size_t)b * 2097152 + (size_t)(n0 + r) * 2048 + t0 + tx] = tile[tx][r];
}

// ---------------------------------------------------------------------------
// Flash attention, S^T scheme, XOR-swizzled LDS tiles (conflict-free b128).
// R2: 8 waves / 512 threads per block, 128 q-rows sharing ONE single-buffered
// K/V tile (R1's double-buffer cost a residency slot: 30%->22% occupancy,
// 252->290 us; reverted). 8-wave sharing halves staging traffic + barriers
// per q-row and raises resident waves/CU 12 -> 16 (VGPR-tier capped).
// Grid (16 qtiles, 32 h, 2 b). Key tile = 64.
// lK stored as [key][chunk ^ (key&15)] (16-B chunks); lV as [d][chunk ^ (d&7)].
// Swizzle applied by permuting global_load_lds SOURCE addresses (dest must
// stay lane-contiguous), un-applied in the ds_read addressing.
// Kept from R1 (VALU cuts): exp2-domain softmax (log2e folded into Q scale),
// defer-max rescale (THR=8 in log2 domain => p <= 2^8), v_cvt_pk_bf16_f32.
// ---------------------------------------------------------------------------
__global__ __launch_bounds__(512) void flash_attn(
    const ushort* __restrict__ Q, const ushort* __restrict__ KV,
    const ushort* __restrict__ Vt, ushort* __restrict__ ctx)
{
    __shared__ __align__(16) ushort lK[64 * 128];    // [key][d-swz] 16 KB
    __shared__ __align__(16) ushort lV[128 * 64];    // [d][s-swz]   16 KB
    __shared__ __align__(16) ushort lP[8 * 16 * 72]; // per-wave [q][72] 18 KB

    const int qt = blockIdx.x, h = blockIdx.y, b = blockIdx.z;
    const int kv = h >> 2;
    const int tid = threadIdx.x, lane = tid & 63, w = tid >> 6;
    const int quad = lane >> 4, l16 = lane & 15;

    const int q0 = qt * 128 + w * 16;
    const size_t qrow = (size_t)(b * 2048 + q0 + l16) * 4096 + h * 128;
    bf16x8 bQ[4];
#pragma unroll
    for (int ks = 0; ks < 4; ks++)
        bQ[ks] = *(const bf16x8*)&Q[qrow + ks * 32 + quad * 8];

    f32x4 o[8];
#pragma unroll
    for (int dc = 0; dc < 8; dc++) o[dc] = (f32x4){0.f, 0.f, 0.f, 0.f};
    float m = -1e30f, l = 0.f;

    const ushort* gK = KV + (size_t)(b * 2048) * 2048 + kv * 128;   // stride 2048
    const ushort* gV = Vt + (size_t)(b * 8 + kv) * 2048 * 128;      // [d][t]
    ushort* pw = &lP[w * 16 * 72];

    // staging decomposition, 512 threads (swizzled source chunks):
    //  K: slot = rep*512+tid = key*16+dslot; key = rep*32+(tid>>4), dslot = tid&15
    //     global d-chunk = dslot ^ (key & 15) = dsub ^ (keyb & 15)   [32 | 16]
    //  V: slot = rep*512+tid = d*8+sslot;    d   = rep*64+(tid>>3), sslot = tid&7
    //     global s-chunk = sslot ^ (d & 7)  = ssub ^ (db & 7)        [64 | 8]
    const int keyb = tid >> 4, dsub = tid & 15;     // keyb 0..31
    const int db   = tid >> 3, ssub = tid & 7;      // db   0..63
    const ushort* baseK = gK + (size_t)keyb * 2048 + (dsub ^ (keyb & 15)) * 8;
    const ushort* baseV = gV + (size_t)db * 2048 + (ssub ^ (db & 7)) * 8;
    char* ldsK = (char*)lK + (tid & 448) * 16;   // wave-uniform sub-base (w*1024 B)
    char* ldsV = (char*)lV + (tid & 448) * 16;

    for (int s0 = 0; s0 < 2048; s0 += 64) {
#pragma unroll
        for (int rep = 0; rep < 2; rep++) {
            __builtin_amdgcn_global_load_lds(
                GLB_AS(baseK + (size_t)(s0 + rep * 32) * 2048),
                LDS_AS(ldsK + rep * 8192), 16, 0, 0);
            __builtin_amdgcn_global_load_lds(
                GLB_AS(baseV + (size_t)rep * 131072 + s0),
                LDS_AS(ldsV + rep * 8192), 16, 0, 0);
        }
        __syncthreads();

        // S^T[key][q]: A = K rows (16 keys/group), B = Q
        f32x4 scT[4];
#pragma unroll
        for (int g = 0; g < 4; g++) scT[g] = (f32x4){0.f, 0.f, 0.f, 0.f};
#pragma unroll
        for (int g = 0; g < 4; g++)
#pragma unroll
            for (int ks = 0; ks < 4; ks++) {
                // key = g*16+l16; chunk ks*4+quad, swizzled by key&15 = l16
                bf16x8 aK = *(const bf16x8*)&lK[(g * 16 + l16) * 128 + ((ks * 4 + quad) ^ l16) * 8];
                scT[g] = __builtin_amdgcn_mfma_f32_16x16x32_bf16(aK, bQ[ks], scT[g], 0, 0, 0);
            }

        // online softmax (exp2 domain): lane holds 16 keys for q = l16
        float tmax = scT[0][0];
#pragma unroll
        for (int g = 0; g < 4; g++)
#pragma unroll
            for (int r = 0; r < 4; r++) tmax = fmaxf(tmax, scT[g][r]);
        tmax = fmaxf(tmax, __shfl_xor(tmax, 16, 64));
        tmax = fmaxf(tmax, __shfl_xor(tmax, 32, 64));

        if (__any(tmax > m + 8.f)) {     // defer-max: skip rescale while bounded
            float mnew = fmaxf(m, tmax);
            float alpha = exp2f(m - mnew);
            m = mnew;
            l *= alpha;
#pragma unroll
            for (int dc = 0; dc < 8; dc++)
#pragma unroll
                for (int r = 0; r < 4; r++) o[dc][r] *= alpha;
        }

        float p[16];
        float ts = 0.f;
#pragma unroll
        for (int i = 0; i < 16; i++) {
            p[i] = exp2f(scT[i >> 2][i & 3] - m);
            ts += p[i];
        }
        ts += __shfl_xor(ts, 16, 64);
        ts += __shfl_xor(ts, 32, 64);
        l += ts;

        // P^T -> LDS [q][s] (s = g*16 + quad*4 + r), b64 writes, stride 72
#pragma unroll
        for (int g = 0; g < 4; g++) {
            uint2 pk;
            pk.x = cvtpk2(p[g * 4 + 0], p[g * 4 + 1]);
            pk.y = cvtpk2(p[g * 4 + 2], p[g * 4 + 3]);
            *(uint2*)&pw[l16 * 72 + g * 16 + quad * 4] = pk;
        }
        bf16x8 bP[2];
#pragma unroll
        for (int c = 0; c < 2; c++)
            bP[c] = *(const bf16x8*)&pw[l16 * 72 + c * 32 + quad * 8];

        // O^T += V^T * P^T
#pragma unroll
        for (int dc = 0; dc < 8; dc++)
#pragma unroll
            for (int c = 0; c < 2; c++) {
                // d = dc*16+l16; chunk c*4+quad, swizzled by d&7 = l16&7
                bf16x8 aV = *(const bf16x8*)&lV[(dc * 16 + l16) * 64 + ((c * 4 + quad) ^ (l16 & 7)) * 8];
                o[dc] = __builtin_amdgcn_mfma_f32_16x16x32_bf16(aV, bP[c], o[dc], 0, 0, 0);
            }
        __syncthreads();
    }

    // epilogue: lane has O^T[d = dc*16+quad*4+r][q = l16]
    float inv = 1.0f / l;
#pragma unroll
    for (int dc = 0; dc < 8; dc++) {
        uint2 pk;
        pk.x = cvtpk2(o[dc][0] * inv, o[dc][1] * inv);
        pk.y = cvtpk2(o[dc][2] * inv, o[dc][3] * inv);
        *(uint2*)&ctx[qrow + dc * 16 + quad * 4] = pk;
    }
}

// ---------------------------------------------------------------------------
extern "C" void kernel_launch(void* const* d_in, const int* in_sizes, int n_in,
                              void* d_out, int out_size, void* d_ws, size_t ws_size,
                              hipStream_t stream)
{
    const float* x    = (const float*)d_in[0];
    const float* wq   = (const float*)d_in[1];
    const float* wk   = (const float*)d_in[2];
    const float* wv   = (const float*)d_in[3];
    const float* wo   = (const float*)d_in[4];
    const float* cosv = (const float*)d_in[7];
    const float* sinv = (const float*)d_in[8];
    float* out = (float*)d_out;

    // workspace (ushort units), 128 MB total via aliasing
    ushort* Xb   = (ushort*)d_ws;                    // 16M: x bf16; later ctx
    ushort* ctx  = Xb;
    ushort* Wbig = Xb   + (size_t)16 * 1024 * 1024;  // 16M: wq, then wo
    ushort* Wsm  = Wbig + (size_t)16 * 1024 * 1024;  //  8M: [wk;wv]; later Vt
    ushort* Vt   = Wsm;
    ushort* Q    = Wsm  + (size_t)8  * 1024 * 1024;  // 16M
    ushort* KV   = Q    + (size_t)16 * 1024 * 1024;  //  8M: [K|V] cols, stride 2048

    dim3 blk(256);
    cast_f2b<<<16384, blk, 0, stream>>>((const float4*)x,  (ushort4*)Xb,   4194304);
    cast_f2b<<<16384, blk, 0, stream>>>((const float4*)wq, (ushort4*)Wbig, 4194304);
    cast_f2b<<<4096,  blk, 0, stream>>>((const float4*)wk, (ushort4*)Wsm,  1048576);
    cast_f2b<<<4096,  blk, 0, stream>>>((const float4*)wv, (ushort4*)(Wsm + (size_t)4194304), 1048576);

    gemm_nt<<<dim3(32, 32), blk, 0, stream>>>(Xb, Wbig, Q,  4096, 4096, 4096);
    gemm_nt<<<dim3(16, 32), blk, 0, stream>>>(Xb, Wsm,  KV, 4096, 2048, 4096);

    cast_f2b<<<16384, blk, 0, stream>>>((const float4*)wo, (ushort4*)Wbig, 4194304);

    // Q scale = 1/sqrt(128) * log2(e)  (softmax runs in exp2 domain)
    rope_kernel<<<8192, blk, 0, stream>>>(Q,  cosv, sinv, 4096, 9,
                                          0.08838834764831845f * 1.4426950408889634f);
    rope_kernel<<<2048, blk, 0, stream>>>(KV, cosv, sinv, 2048, 7, 1.0f);
    transpose_v<<<dim3(32, 128), blk, 0, stream>>>(KV, Vt);

    flash_attn<<<dim3(16, 32, 2), dim3(512), 0, stream>>>(Q, KV, Vt, ctx);

    gemm_nt<<<dim3(32, 32), blk, 0, stream>>>(ctx, Wbig, out, 4096, 4096, 4096);
}

// Round 3
// 771.773 us; speedup vs baseline: 1.3351x; 1.2483x over previous
//
#include <hip/hip_runtime.h>
#include <hip/hip_bf16.h>
#include <stdint.h>

// Attention_47528108097749: llama attention block. f32 in/out, bf16 MFMA inside.
// B=2, T=2048, D=4096, H=32, KV=8, HD=128. start_pos=0, mask unused (full attn).

typedef short bf16x8 __attribute__((ext_vector_type(8)));
typedef float f32x4  __attribute__((ext_vector_type(4)));

#define GLB_AS(p) ((__attribute__((address_space(1))) void*)(p))
#define LDS_AS(p) ((__attribute__((address_space(3))) void*)(p))

__device__ __forceinline__ float bf2f(ushort u) {
    union { unsigned int i; float f; } v; v.i = ((unsigned int)u) << 16; return v.f;
}
__device__ __forceinline__ ushort f2bf(float f) {
    union { float f; unsigned int i; } v; v.f = f;
    unsigned int r = v.i + 0x7FFFu + ((v.i >> 16) & 1u);   // RNE
    return (ushort)(r >> 16);
}
__device__ __forceinline__ unsigned int pk_bf16(float a, float b) {
    return (unsigned int)f2bf(a) | ((unsigned int)f2bf(b) << 16);
}
// HW packed f32->bf16 (RNE); lo = src0
__device__ __forceinline__ unsigned int cvtpk2(float lo, float hi) {
    unsigned int r;
    asm("v_cvt_pk_bf16_f32 %0, %1, %2" : "=v"(r) : "v"(lo), "v"(hi));
    return r;
}
__device__ __forceinline__ void store_c(ushort* p, float v) { *p = f2bf(v); }
__device__ __forceinline__ void store_c(float*  p, float v) { *p = v; }

// raw barrier with compiler memory fences (does NOT drain vmcnt like __syncthreads)
__device__ __forceinline__ void barr() {
    asm volatile("" ::: "memory");
    __builtin_amdgcn_s_barrier();
    asm volatile("" ::: "memory");
}

// ---------------------------------------------------------------------------
__global__ __launch_bounds__(256) void cast_f2b(
    const float4* __restrict__ src, ushort4* __restrict__ dst, int n4)
{
    int i = blockIdx.x * 256 + threadIdx.x;
    if (i < n4) {
        float4 v = src[i];
        ushort4 o;
        o.x = f2bf(v.x); o.y = f2bf(v.y); o.z = f2bf(v.z); o.w = f2bf(v.w);
        dst[i] = o;
    }
}

// ---------------------------------------------------------------------------
// 256^2 8-phase NT GEMM (m201 template, plain HIP): C[m][n] = sum_k A[m][k]*B[n][k].
// BM=BN=256, BK=64, 512 thr / 8 waves (2M x 4N), LDS 128 KiB:
//   2 bufs x {Ah0,Ah1,Bh0,Bh1} x 16 KiB (half = 128 rows x 64 cols bf16).
// Per K-tile, 4 quadrant phases (Mh,Nh): (0,0)->(0,1)->(1,1)->(1,0).
//   A-frags reused across the 2 phases sharing Mh, B0-frags kept P1->P4,
//   so each LDS half is ds_read in EXACTLY ONE phase -> its slot is free for
//   staging K-tile t+2 from the next phase on (stages: P2 = A0+B0, P3 = B1,
//   P4 = A1). Counted s_waitcnt vmcnt(8) gates only at end of P4/P8
//   (8 = loads issued after the half-tiles the next phase needs).
// T2 chunk swizzle: storage[row][c] = global[row][c ^ (row&7)] (16-B chunks),
//   applied on the global SOURCE of global_load_lds (dest stays linear) and
//   un-applied in ds_read addressing.
// T1 XCD swizzle (nwg % 8 == 0 for all shapes here). T5 setprio around MFMA.
// ---------------------------------------------------------------------------
enum { OFF_A0 = 0, OFF_A1 = 16384, OFF_B0 = 32768, OFF_B1 = 49152, BUFSZ = 65536 };

__device__ __forceinline__ void rdA(const char* half, bf16x8 (&a)[4][2],
                                    int wm, int quad, int l16) {
    const int cx = l16 & 7;
#pragma unroll
    for (int m2 = 0; m2 < 4; m2++)
#pragma unroll
        for (int ks = 0; ks < 2; ks++)
            a[m2][ks] = *(const bf16x8*)(half + (wm * 64 + m2 * 16 + l16) * 128
                                              + (((ks * 4 + quad) ^ cx) * 16));
}
__device__ __forceinline__ void rdB(const char* half, bf16x8 (&b)[2][2],
                                    int wn, int quad, int l16) {
    const int cx = l16 & 7;
#pragma unroll
    for (int n2 = 0; n2 < 2; n2++)
#pragma unroll
        for (int ks = 0; ks < 2; ks++)
            b[n2][ks] = *(const bf16x8*)(half + (wn * 32 + n2 * 16 + l16) * 128
                                              + (((ks * 4 + quad) ^ cx) * 16));
}
template <int MH, int NH>
__device__ __forceinline__ void mmq(f32x4 (&acc)[2][2][4][2],
                                    const bf16x8 (&a)[4][2], const bf16x8 (&b)[2][2]) {
    __builtin_amdgcn_s_setprio(1);
#pragma unroll
    for (int m2 = 0; m2 < 4; m2++)
#pragma unroll
        for (int n2 = 0; n2 < 2; n2++)
#pragma unroll
            for (int ks = 0; ks < 2; ks++)
                acc[MH][NH][m2][n2] = __builtin_amdgcn_mfma_f32_16x16x32_bf16(
                    a[m2][ks], b[n2][ks], acc[MH][NH][m2][n2], 0, 0, 0);
    __builtin_amdgcn_s_setprio(0);
}
// one half-tile = 128 rows x 64 cols = 2 global_load_lds per thread
__device__ __forceinline__ void stage_half(const char* src, char* dst, size_t kb) {
    __builtin_amdgcn_global_load_lds(GLB_AS(src),           LDS_AS(dst),        16, 0, 0);
    __builtin_amdgcn_global_load_lds(GLB_AS(src + 64 * kb), LDS_AS(dst + 8192), 16, 0, 0);
}

#define GATE8 asm volatile("s_waitcnt vmcnt(8)" ::: "memory")
#define GATE0 asm volatile("s_waitcnt vmcnt(0)" ::: "memory")
#define GATEN ((void)0)

// 4 phases of one K-tile living in buffer LBUF; optionally stage K-tile at
// byte-offset KO into the same buffer's just-freed slots; GATE at end of P4.
#define DO_TILE(LBUF, KO, DO_STAGE, GATE)                                        \
    {                                                                            \
        const char* Lb = lds + (LBUF) * BUFSZ;                                   \
        char* Sb = ldsW + (LBUF) * BUFSZ;                                        \
        /* P1: quadrant (0,0) */                                                 \
        rdA(Lb + OFF_A0, a, wm, quad, l16);                                      \
        rdB(Lb + OFF_B0, b0, wn, quad, l16);                                     \
        barr();                                                                  \
        mmq<0, 0>(acc, a, b0);                                                   \
        barr();                                                                  \
        /* P2: quadrant (0,1); Ah0/Bh0 now free */                               \
        rdB(Lb + OFF_B1, b1, wn, quad, l16);                                     \
        if (DO_STAGE) {                                                          \
            stage_half(aSrc + (KO), Sb + OFF_A0, kb);                            \
            stage_half(bSrc + (KO), Sb + OFF_B0, kb);                            \
        }                                                                        \
        barr();                                                                  \
        mmq<0, 1>(acc, a, b1);                                                   \
        barr();                                                                  \
        /* P3: quadrant (1,1); Bh1 free after this phase's reads */              \
        rdA(Lb + OFF_A1, a, wm, quad, l16);                                      \
        if (DO_STAGE) stage_half(bSrc + 128 * kb + (KO), Sb + OFF_B1, kb);       \
        barr();                                                                  \
        mmq<1, 1>(acc, a, b1);                                                   \
        barr();                                                                  \
        /* P4: quadrant (1,0); no ds_reads (A1 + kept B0) */                     \
        if (DO_STAGE) stage_half(aSrc + 128 * kb + (KO), Sb + OFF_A1, kb);       \
        barr();                                                                  \
        mmq<1, 0>(acc, a, b0);                                                   \
        GATE;                                                                    \
        barr();                                                                  \
    }

template <typename OT>
__global__ __launch_bounds__(512, 2) void gemm_nt256(
    const ushort* __restrict__ A, const ushort* __restrict__ B,
    OT* __restrict__ C, int N, int K)
{
    __shared__ __align__(16) char lds[131072];

    const int tid = threadIdx.x, lane = tid & 63, w = tid >> 6;
    const int wm = w >> 2, wn = w & 3;
    const int quad = lane >> 4, l16 = lane & 15;

    // T1: bijective XCD swizzle (gridDim.x % 8 == 0 for all shapes here)
    const int nwg = gridDim.x;
    const int swz = ((int)blockIdx.x & 7) * (nwg >> 3) + ((int)blockIdx.x >> 3);
    const int nx  = N >> 8;
    const int bm  = (swz / nx) * 256, bn = (swz % nx) * 256;

    const size_t kb = (size_t)K * 2;   // row stride, bytes

    // staging: thread -> dest slot (row = rep*64 + (tid>>3), chunk = tid&7);
    // source chunk pre-swizzled so storage chunk c holds global chunk c^(row&7)
    const int srow = tid >> 3;
    const int gch  = (tid & 7) ^ (srow & 7);
    const char* aSrc = (const char*)A + (size_t)(bm + srow) * kb + gch * 16;
    const char* bSrc = (const char*)B + (size_t)(bn + srow) * kb + gch * 16;
    char* ldsW = lds + w * 1024;       // wave-uniform dest base (+lane*16 by HW)

    f32x4 acc[2][2][4][2];
#pragma unroll
    for (int i = 0; i < 2; i++)
#pragma unroll
        for (int j = 0; j < 2; j++)
#pragma unroll
            for (int m2 = 0; m2 < 4; m2++)
#pragma unroll
                for (int n2 = 0; n2 < 2; n2++)
                    acc[i][j][m2][n2] = (f32x4){0.f, 0.f, 0.f, 0.f};

    bf16x8 a[4][2], b0[2][2], b1[2][2];

    // prologue: stage K-tiles 0 (buf0) and 1 (buf1); wait tile0 (8 newest in flight)
    stage_half(aSrc,                ldsW + OFF_A0, kb);
    stage_half(aSrc + 128 * kb,     ldsW + OFF_A1, kb);
    stage_half(bSrc,                ldsW + OFF_B0, kb);
    stage_half(bSrc + 128 * kb,     ldsW + OFF_B1, kb);
    stage_half(aSrc + 128,            ldsW + BUFSZ + OFF_A0, kb);
    stage_half(aSrc + 128 * kb + 128, ldsW + BUFSZ + OFF_A1, kb);
    stage_half(bSrc + 128,            ldsW + BUFSZ + OFF_B0, kb);
    stage_half(bSrc + 128 * kb + 128, ldsW + BUFSZ + OFF_B1, kb);
    GATE8;
    barr();

    // main: 31 iters x 2 K-tiles; iter it computes tiles 2it,2it+1 and stages
    // tiles 2it+2 (into buf0) and 2it+3 (into buf1). K=4096 -> 64 tiles.
    int ko = 256;                      // byte offset of K-tile 2 (tile = 128 B)
    for (int it = 0; it < 31; ++it, ko += 256) {
        DO_TILE(0, ko,       true, GATE8);
        DO_TILE(1, ko + 128, true, GATE8);
    }
    // tail: tiles 62, 63 — no staging; drain before reading tile 63
    DO_TILE(0, 0, false, GATE0);
    DO_TILE(1, 0, false, GATEN);

    // epilogue: C row = A side (quad*4+r), col = B side (l16)  [m89 layout]
#pragma unroll
    for (int MH = 0; MH < 2; MH++)
#pragma unroll
        for (int NH = 0; NH < 2; NH++)
#pragma unroll
            for (int m2 = 0; m2 < 4; m2++)
#pragma unroll
                for (int n2 = 0; n2 < 2; n2++)
#pragma unroll
                    for (int r = 0; r < 4; r++) {
                        int row = bm + MH * 128 + wm * 64 + m2 * 16 + quad * 4 + r;
                        int col = bn + NH * 128 + wn * 32 + n2 * 16 + l16;
                        store_c(&C[(size_t)row * N + col], acc[MH][NH][m2][n2][r]);
                    }
}

// ---------------------------------------------------------------------------
// RoPE in-place on bf16 X; row stride ldx, cos/sin f32 [2048][64].
// Scale folds attention 1/sqrt(HD) (and log2(e) for exp2-domain softmax) into Q.
// ---------------------------------------------------------------------------
__global__ __launch_bounds__(256) void rope_kernel(
    ushort* __restrict__ X, const float* __restrict__ cosv,
    const float* __restrict__ sinv, int ldx, int tprs, float scale)
{
    int gid = blockIdx.x * 256 + threadIdx.x;
    int m  = gid >> tprs;
    int pi = (gid & ((1 << tprs) - 1)) * 4;
    int t  = m & 2047;
    int i  = pi & 63;
    float4 c4 = *(const float4*)&cosv[t * 64 + i];
    float4 s4 = *(const float4*)&sinv[t * 64 + i];
    ushort* px = X + (size_t)m * ldx + pi * 2;
    uint4 d = *(const uint4*)px;
    unsigned int parts[4] = {d.x, d.y, d.z, d.w};
    float cc[4] = {c4.x, c4.y, c4.z, c4.w};
    float ss[4] = {s4.x, s4.y, s4.z, s4.w};
#pragma unroll
    for (int p = 0; p < 4; p++) {
        float re = bf2f((ushort)(parts[p] & 0xffffu));
        float im = bf2f((ushort)(parts[p] >> 16));
        float re2 = (re * cc[p] - im * ss[p]) * scale;
        float im2 = (re * ss[p] + im * cc[p]) * scale;
        parts[p] = pk_bf16(re2, im2);
    }
    *(uint4*)px = make_uint4(parts[0], parts[1], parts[2], parts[3]);
}

// ---------------------------------------------------------------------------
// V transpose out of fused KV: KV rows (b,t) stride 2048, V = cols 1024..2047.
// Vt[b][n][t], n=(kv,d) in 0..1023.
// ---------------------------------------------------------------------------
__global__ __launch_bounds__(256) void transpose_v(
    const ushort* __restrict__ KV, ushort* __restrict__ Vt)
{
    __shared__ ushort tile[32][33];
    int n0 = blockIdx.x * 32, m0 = blockIdx.y * 32;
    int tx = threadIdx.x & 31, ty = threadIdx.x >> 5;
#pragma unroll
    for (int r = ty; r < 32; r += 8)
        tile[r][tx] = KV[(size_t)(m0 + r) * 2048 + 1024 + n0 + tx];
    __syncthreads();
    int b  = m0 >> 11;
    int t0 = m0 & 2047;
#pragma unroll
    for (int r = ty; r < 32; r += 8)
        Vt[(size_t)b * 2097152 + (size_t)(n0 + r) * 2048 + t0 + tx] = tile[tx][r];
}

// ---------------------------------------------------------------------------
// Flash attention, S^T scheme, XOR-swizzled LDS tiles (conflict-free b128).
// R2 structure (verified): 8 waves / 512 threads, 128 q-rows sharing ONE
// single-buffered K/V tile. Grid (16 qtiles, 32 h, 2 b). Key tile = 64.
// exp2-domain softmax (log2e folded into Q scale), defer-max (THR=8),
// v_cvt_pk_bf16_f32 packing.
// ---------------------------------------------------------------------------
__global__ __launch_bounds__(512) void flash_attn(
    const ushort* __restrict__ Q, const ushort* __restrict__ KV,
    const ushort* __restrict__ Vt, ushort* __restrict__ ctx)
{
    __shared__ __align__(16) ushort lK[64 * 128];    // [key][d-swz] 16 KB
    __shared__ __align__(16) ushort lV[128 * 64];    // [d][s-swz]   16 KB
    __shared__ __align__(16) ushort lP[8 * 16 * 72]; // per-wave [q][72] 18 KB

    const int qt = blockIdx.x, h = blockIdx.y, b = blockIdx.z;
    const int kv = h >> 2;
    const int tid = threadIdx.x, lane = tid & 63, w = tid >> 6;
    const int quad = lane >> 4, l16 = lane & 15;

    const int q0 = qt * 128 + w * 16;
    const size_t qrow = (size_t)(b * 2048 + q0 + l16) * 4096 + h * 128;
    bf16x8 bQ[4];
#pragma unroll
    for (int ks = 0; ks < 4; ks++)
        bQ[ks] = *(const bf16x8*)&Q[qrow + ks * 32 + quad * 8];

    f32x4 o[8];
#pragma unroll
    for (int dc = 0; dc < 8; dc++) o[dc] = (f32x4){0.f, 0.f, 0.f, 0.f};
    float m = -1e30f, l = 0.f;

    const ushort* gK = KV + (size_t)(b * 2048) * 2048 + kv * 128;   // stride 2048
    const ushort* gV = Vt + (size_t)(b * 8 + kv) * 2048 * 128;      // [d][t]
    ushort* pw = &lP[w * 16 * 72];

    const int keyb = tid >> 4, dsub = tid & 15;     // keyb 0..31
    const int db   = tid >> 3, ssub = tid & 7;      // db   0..63
    const ushort* baseK = gK + (size_t)keyb * 2048 + (dsub ^ (keyb & 15)) * 8;
    const ushort* baseV = gV + (size_t)db * 2048 + (ssub ^ (db & 7)) * 8;
    char* ldsK = (char*)lK + (tid & 448) * 16;   // wave-uniform sub-base
    char* ldsV = (char*)lV + (tid & 448) * 16;

    for (int s0 = 0; s0 < 2048; s0 += 64) {
#pragma unroll
        for (int rep = 0; rep < 2; rep++) {
            __builtin_amdgcn_global_load_lds(
                GLB_AS(baseK + (size_t)(s0 + rep * 32) * 2048),
                LDS_AS(ldsK + rep * 8192), 16, 0, 0);
            __builtin_amdgcn_global_load_lds(
                GLB_AS(baseV + (size_t)rep * 131072 + s0),
                LDS_AS(ldsV + rep * 8192), 16, 0, 0);
        }
        __syncthreads();

        // S^T[key][q]: A = K rows (16 keys/group), B = Q
        f32x4 scT[4];
#pragma unroll
        for (int g = 0; g < 4; g++) scT[g] = (f32x4){0.f, 0.f, 0.f, 0.f};
#pragma unroll
        for (int g = 0; g < 4; g++)
#pragma unroll
            for (int ks = 0; ks < 4; ks++) {
                bf16x8 aK = *(const bf16x8*)&lK[(g * 16 + l16) * 128 + ((ks * 4 + quad) ^ l16) * 8];
                scT[g] = __builtin_amdgcn_mfma_f32_16x16x32_bf16(aK, bQ[ks], scT[g], 0, 0, 0);
            }

        // online softmax (exp2 domain): lane holds 16 keys for q = l16
        float tmax = scT[0][0];
#pragma unroll
        for (int g = 0; g < 4; g++)
#pragma unroll
            for (int r = 0; r < 4; r++) tmax = fmaxf(tmax, scT[g][r]);
        tmax = fmaxf(tmax, __shfl_xor(tmax, 16, 64));
        tmax = fmaxf(tmax, __shfl_xor(tmax, 32, 64));

        if (__any(tmax > m + 8.f)) {     // defer-max: skip rescale while bounded
            float mnew = fmaxf(m, tmax);
            float alpha = exp2f(m - mnew);
            m = mnew;
            l *= alpha;
#pragma unroll
            for (int dc = 0; dc < 8; dc++)
#pragma unroll
                for (int r = 0; r < 4; r++) o[dc][r] *= alpha;
        }

        float p[16];
        float ts = 0.f;
#pragma unroll
        for (int i = 0; i < 16; i++) {
            p[i] = exp2f(scT[i >> 2][i & 3] - m);
            ts += p[i];
        }
        ts += __shfl_xor(ts, 16, 64);
        ts += __shfl_xor(ts, 32, 64);
        l += ts;

        // P^T -> LDS [q][s] (s = g*16 + quad*4 + r), b64 writes, stride 72
#pragma unroll
        for (int g = 0; g < 4; g++) {
            uint2 pk;
            pk.x = cvtpk2(p[g * 4 + 0], p[g * 4 + 1]);
            pk.y = cvtpk2(p[g * 4 + 2], p[g * 4 + 3]);
            *(uint2*)&pw[l16 * 72 + g * 16 + quad * 4] = pk;
        }
        bf16x8 bP[2];
#pragma unroll
        for (int c = 0; c < 2; c++)
            bP[c] = *(const bf16x8*)&pw[l16 * 72 + c * 32 + quad * 8];

        // O^T += V^T * P^T
#pragma unroll
        for (int dc = 0; dc < 8; dc++)
#pragma unroll
            for (int c = 0; c < 2; c++) {
                bf16x8 aV = *(const bf16x8*)&lV[(dc * 16 + l16) * 64 + ((c * 4 + quad) ^ (l16 & 7)) * 8];
                o[dc] = __builtin_amdgcn_mfma_f32_16x16x32_bf16(aV, bP[c], o[dc], 0, 0, 0);
            }
        __syncthreads();
    }

    // epilogue: lane has O^T[d = dc*16+quad*4+r][q = l16]
    float inv = 1.0f / l;
#pragma unroll
    for (int dc = 0; dc < 8; dc++) {
        uint2 pk;
        pk.x = cvtpk2(o[dc][0] * inv, o[dc][1] * inv);
        pk.y = cvtpk2(o[dc][2] * inv, o[dc][3] * inv);
        *(uint2*)&ctx[qrow + dc * 16 + quad * 4] = pk;
    }
}

// ---------------------------------------------------------------------------
extern "C" void kernel_launch(void* const* d_in, const int* in_sizes, int n_in,
                              void* d_out, int out_size, void* d_ws, size_t ws_size,
                              hipStream_t stream)
{
    const float* x    = (const float*)d_in[0];
    const float* wq   = (const float*)d_in[1];
    const float* wk   = (const float*)d_in[2];
    const float* wv   = (const float*)d_in[3];
    const float* wo   = (const float*)d_in[4];
    const float* cosv = (const float*)d_in[7];
    const float* sinv = (const float*)d_in[8];
    float* out = (float*)d_out;

    // workspace (ushort units), 128 MB total via aliasing
    ushort* Xb   = (ushort*)d_ws;                    // 16M: x bf16; later ctx
    ushort* ctx  = Xb;
    ushort* Wbig = Xb   + (size_t)16 * 1024 * 1024;  // 16M: wq, then wo
    ushort* Wsm  = Wbig + (size_t)16 * 1024 * 1024;  //  8M: [wk;wv]; later Vt
    ushort* Vt   = Wsm;
    ushort* Q    = Wsm  + (size_t)8  * 1024 * 1024;  // 16M
    ushort* KV   = Q    + (size_t)16 * 1024 * 1024;  //  8M: [K|V] cols, stride 2048

    dim3 blk(256);
    cast_f2b<<<16384, blk, 0, stream>>>((const float4*)x,  (ushort4*)Xb,   4194304);
    cast_f2b<<<16384, blk, 0, stream>>>((const float4*)wq, (ushort4*)Wbig, 4194304);
    cast_f2b<<<4096,  blk, 0, stream>>>((const float4*)wk, (ushort4*)Wsm,  1048576);
    cast_f2b<<<4096,  blk, 0, stream>>>((const float4*)wv, (ushort4*)(Wsm + (size_t)4194304), 1048576);

    gemm_nt256<<<dim3(256), dim3(512), 0, stream>>>(Xb, Wbig, Q,  4096, 4096);
    gemm_nt256<<<dim3(128), dim3(512), 0, stream>>>(Xb, Wsm,  KV, 2048, 4096);

    cast_f2b<<<16384, blk, 0, stream>>>((const float4*)wo, (ushort4*)Wbig, 4194304);

    // Q scale = 1/sqrt(128) * log2(e)  (softmax runs in exp2 domain)
    rope_kernel<<<8192, blk, 0, stream>>>(Q,  cosv, sinv, 4096, 9,
                                          0.08838834764831845f * 1.4426950408889634f);
    rope_kernel<<<2048, blk, 0, stream>>>(KV, cosv, sinv, 2048, 7, 1.0f);
    transpose_v<<<dim3(32, 128), blk, 0, stream>>>(KV, Vt);

    flash_attn<<<dim3(16, 32, 2), dim3(512), 0, stream>>>(Q, KV, Vt, ctx);

    gemm_nt256<<<dim3(256), dim3(512), 0, stream>>>(ctx, Wbig, out, 4096, 4096);
}